// Round 3
// baseline (100.086 us; speedup 1.0000x reference)
//
#include <hip/hip_runtime.h>
#include <hip/hip_bf16.h>

// Problem: B=8, S=4096, D=1024. Inputs: x0[B,S,D] f32, x1[B,S,D] f32,
// skipping_probs[B,S] f32 (unused — keep mask already sampled), keep[B,S] i32.
// Output: two [B,S,D] f32 tensors, concatenated flat in d_out: kept rows
// compacted to the front (stable order), tail rows zeroed.
//
// Pure data movement. Minimal traffic: 268 MB writes + ~201 MB reads (~75% keep
// rate) = ~470 MB -> floor ~75 us at the 6.3 TB/s copy ceiling.
// R3: contiguous 16-rows-per-block mapping (64 KiB contiguous write burst per
// tensor per block) + LDS-staged src indices to break the dependent-load chain.

#define BB 8
#define SS 4096
#define DD 1024
#define D4 (DD / 4)   // 256 float4 per row
#define RPB 16        // rows per copy block (16 | 4096 -> one batch per block)

typedef float f4 __attribute__((ext_vector_type(4)));

// ---------------- Kernel A: per-batch stable compaction index ----------------
// grid = B blocks, 1024 threads. Each thread owns 4 consecutive timesteps.
// Produces src_idx[b*S + r] = source timestep of the r-th kept row, and
// n_kept[b]. Stable: scan is in timestep order.
__global__ __launch_bounds__(1024) void scan_kernel(
    const int* __restrict__ keep,
    int* __restrict__ src_idx,
    int* __restrict__ n_kept)
{
    const int b = blockIdx.x;
    const int t = threadIdx.x;           // 0..1023
    __shared__ int wave_sums[16];

    const int* krow = keep + b * SS;
    const int base = t * 4;
    const int k0 = krow[base + 0];
    const int k1 = krow[base + 1];
    const int k2 = krow[base + 2];
    const int k3 = krow[base + 3];
    const int local = k0 + k1 + k2 + k3;

    const int lane = t & 63;
    const int wid  = t >> 6;             // 0..15

    // wave-inclusive scan of per-thread totals (64 lanes)
    int incl = local;
    #pragma unroll
    for (int off = 1; off < 64; off <<= 1) {
        int v = __shfl_up(incl, off, 64);
        if (lane >= off) incl += v;
    }
    if (lane == 63) wave_sums[wid] = incl;
    __syncthreads();

    // inclusive scan of the 16 wave totals (lanes 0..15 of wave 0)
    if (t < 16) {
        int v = wave_sums[t];
        #pragma unroll
        for (int off = 1; off < 16; off <<= 1) {
            int u = __shfl_up(v, off, 64);
            if (t >= off) v += u;
        }
        wave_sums[t] = v;
    }
    __syncthreads();

    const int wave_off = (wid > 0) ? wave_sums[wid - 1] : 0;
    int d = wave_off + incl - local;     // exclusive prefix for this thread's 4

    int* dst = src_idx + b * SS;
    if (k0) dst[d++] = base + 0;
    if (k1) dst[d++] = base + 1;
    if (k2) dst[d++] = base + 2;
    if (k3) dst[d++] = base + 3;

    if (t == 0) n_kept[b] = wave_sums[15];
}

// ---------------- Kernel B: destination-indexed row copy ----------------
// 2048 blocks x 256 threads; block handles RPB=16 CONSECUTIVE output rows
// (one batch per block). Per row: 256 threads x 1 float4 per tensor
// (256*16B = 4 KiB = one full row) -> 64 KiB contiguous write burst per
// tensor per block. src indices staged through LDS once (single sync),
// then a fully-unrolled row loop the compiler can pipeline.
// Rows r < n_kept[b] gather their source row; tail rows write zeros.
// Every output element written exactly once per call -> deterministic
// across graph replays.
__global__ __launch_bounds__(256) void compact_copy_kernel(
    const f4* __restrict__ x0,
    const f4* __restrict__ x1,
    const int* __restrict__ src_idx,
    const int* __restrict__ n_kept,
    f4* __restrict__ out0,
    f4* __restrict__ out1)
{
    const int t = threadIdx.x;               // 0..255
    const int base_row = blockIdx.x * RPB;   // first output row of this block
    const int b  = base_row >> 12;           // batch (uniform: 16 | 4096)
    const int r0 = base_row & (SS - 1);      // first r within batch

    __shared__ int sidx[RPB];
    if (t < RPB) sidx[t] = src_idx[base_row + t];  // tail entries unused garbage
    const int nk = n_kept[b];
    __syncthreads();

    const int src_row_base = b * SS * D4 + t;

    #pragma unroll
    for (int i = 0; i < RPB; ++i) {
        const int dst_off = (base_row + i) * D4 + t;
        if (r0 + i < nk) {
            const int src_off = src_row_base + sidx[i] * D4;
            f4 v0 = __builtin_nontemporal_load(&x0[src_off]);
            f4 v1 = __builtin_nontemporal_load(&x1[src_off]);
            __builtin_nontemporal_store(v0, &out0[dst_off]);
            __builtin_nontemporal_store(v1, &out1[dst_off]);
        } else {
            f4 z = {0.f, 0.f, 0.f, 0.f};
            __builtin_nontemporal_store(z, &out0[dst_off]);
            __builtin_nontemporal_store(z, &out1[dst_off]);
        }
    }
}

extern "C" void kernel_launch(void* const* d_in, const int* in_sizes, int n_in,
                              void* d_out, int out_size, void* d_ws, size_t ws_size,
                              hipStream_t stream) {
    const f4* x0  = (const f4*)d_in[0];
    const f4* x1  = (const f4*)d_in[1];
    // d_in[2] = skipping_probs (unused: keep mask is pre-sampled)
    const int* keep = (const int*)d_in[3];

    float* out = (float*)d_out;
    f4* out0 = (f4*)out;
    f4* out1 = (f4*)(out + (size_t)BB * SS * DD);

    int* src_idx = (int*)d_ws;                 // B*S ints = 128 KiB
    int* n_kept  = src_idx + BB * SS;          // B ints

    scan_kernel<<<BB, 1024, 0, stream>>>(keep, src_idx, n_kept);
    compact_copy_kernel<<<(BB * SS) / RPB, 256, 0, stream>>>(
        x0, x1, src_idx, n_kept, out0, out1);
}

// Round 4
// 88.609 us; speedup vs baseline: 1.1295x; 1.1295x over previous
//
#include <hip/hip_runtime.h>
#include <hip/hip_bf16.h>

// Problem: B=8, S=4096, D=1024. Inputs: x0[B,S,D] f32, x1[B,S,D] f32,
// skipping_probs[B,S] f32 (unused — keep mask already sampled), keep[B,S] i32.
// Output: two [B,S,D] f32 tensors, concatenated flat in d_out: kept rows
// compacted to the front (stable order), tail rows zeroed.
//
// Pure data movement: 268 MB writes + ~201 MB reads (~75% keep) = ~470 MB
// -> ~75 us floor at 6.3 TB/s. R4: single FUSED kernel — each block
// recomputes the per-batch compaction scan from keep[b,:] (16 KB, L2-hot,
// VALU is idle anyway) into LDS, eliminating the separate scan kernel and
// its launch bubble. Copy uses R2's proven batch-local grid-stride mapping
// (collective sliding contiguous write window).

#define BB 8
#define SS 4096
#define DD 1024
#define D4 (DD / 4)          // 256 float4 per row
#define BPB 256              // blocks per batch
#define RPB (SS / BPB)       // 16 rows per block, stride BPB

typedef float f4 __attribute__((ext_vector_type(4)));

__global__ __launch_bounds__(256) void fused_compact_kernel(
    const f4* __restrict__ x0,
    const f4* __restrict__ x1,
    const int* __restrict__ keep,
    f4* __restrict__ out0,
    f4* __restrict__ out1)
{
    __shared__ int lds_src[SS];      // dst r -> src s map for this batch (16 KB)
    __shared__ int wave_sums[4];

    const int t = threadIdx.x;               // 0..255
    const int b = blockIdx.x >> 8;           // batch (8)
    const int j = blockIdx.x & (BPB - 1);    // 0..255, stride offset in batch

    // ---- Phase 1: block-wide stable compaction scan of keep[b, :] ----
    // Thread t owns 16 consecutive timesteps [16t, 16t+16). 16 KB of int4
    // loads, L1/L2-resident (only 8 distinct rows chip-wide).
    const int4* krow4 = (const int4*)(keep + b * SS);
    int kk[16];
    {
        const int4 a0 = krow4[4 * t + 0];
        const int4 a1 = krow4[4 * t + 1];
        const int4 a2 = krow4[4 * t + 2];
        const int4 a3 = krow4[4 * t + 3];
        kk[0]  = a0.x; kk[1]  = a0.y; kk[2]  = a0.z; kk[3]  = a0.w;
        kk[4]  = a1.x; kk[5]  = a1.y; kk[6]  = a1.z; kk[7]  = a1.w;
        kk[8]  = a2.x; kk[9]  = a2.y; kk[10] = a2.z; kk[11] = a2.w;
        kk[12] = a3.x; kk[13] = a3.y; kk[14] = a3.z; kk[15] = a3.w;
    }
    int local = 0;
    #pragma unroll
    for (int q = 0; q < 16; ++q) local += kk[q];

    const int lane = t & 63;
    const int wid  = t >> 6;                 // 0..3

    int incl = local;                        // wave-inclusive scan (64 lanes)
    #pragma unroll
    for (int off = 1; off < 64; off <<= 1) {
        int v = __shfl_up(incl, off, 64);
        if (lane >= off) incl += v;
    }
    if (lane == 63) wave_sums[wid] = incl;
    __syncthreads();

    int wave_off = 0, nk = 0;
    #pragma unroll
    for (int w = 0; w < 4; ++w) {
        const int v = wave_sums[w];
        if (w < wid) wave_off += v;
        nk += v;
    }

    int d = wave_off + incl - local;         // exclusive prefix for this thread
    const int base_s = t * 16;
    #pragma unroll
    for (int q = 0; q < 16; ++q) {
        if (kk[q]) lds_src[d++] = base_s + q;
    }
    __syncthreads();

    // ---- Phase 2: batch-local grid-stride gather-copy ----
    // Block j handles rows j, j+256, ..., j+3840. At each iteration the 256
    // blocks of a batch collectively write one contiguous 1 MB sliding window.
    const int batch_base = b * SS * D4 + t;

    for (int i = 0; i < RPB; ++i) {
        const int r = j + (i << 8);          // output row within batch
        const int dst_off = batch_base + r * D4;
        if (r < nk) {
            const int s = lds_src[r];        // LDS broadcast (uniform addr)
            const int src_off = batch_base + s * D4;
            f4 v0 = __builtin_nontemporal_load(&x0[src_off]);
            f4 v1 = __builtin_nontemporal_load(&x1[src_off]);
            __builtin_nontemporal_store(v0, &out0[dst_off]);
            __builtin_nontemporal_store(v1, &out1[dst_off]);
        } else {
            const f4 z = {0.f, 0.f, 0.f, 0.f};
            __builtin_nontemporal_store(z, &out0[dst_off]);
            __builtin_nontemporal_store(z, &out1[dst_off]);
        }
    }
}

extern "C" void kernel_launch(void* const* d_in, const int* in_sizes, int n_in,
                              void* d_out, int out_size, void* d_ws, size_t ws_size,
                              hipStream_t stream) {
    const f4* x0  = (const f4*)d_in[0];
    const f4* x1  = (const f4*)d_in[1];
    // d_in[2] = skipping_probs (unused: keep mask is pre-sampled)
    const int* keep = (const int*)d_in[3];

    float* out = (float*)d_out;
    f4* out0 = (f4*)out;
    f4* out1 = (f4*)(out + (size_t)BB * SS * DD);

    fused_compact_kernel<<<BB * BPB, 256, 0, stream>>>(x0, x1, keep, out0, out1);
}